// Round 5
// baseline (683.237 us; speedup 1.0000x reference)
//
#include <hip/hip_runtime.h>

// F0 via autocorrelation argmax — round 5: shuffle reductions, minimal LDS.
//   SR=16000, HOP=256, FRAME_LEN=512, pad=256, T=163840, B=64, n_frames=641
//   lags p in [32,256), 224 lags. Per-frame normalization is a positive
//   scalar -> argmax of RAW autocorrelation equals reference argmax.
//
// Round-4 lesson (counters): 30 KB LDS partial array -> 4 blocks/CU (32%
// occupancy) and ~12 barriers -> VALUBusy 54%. Fix: the 16 t-segments of a
// lag group are consecutive lanes of ONE wave, so seg-sum is an in-wave
// shfl_xor butterfly (15 shuffles, fixed balanced-tree order); top-2 is a
// 64-lane butterfly + 4-entry LDS merge. 3 barriers total, ~2.5 KB LDS.
//
// Numerics: fp32 result accepted iff top1-top2 gap > GAP_B (rigorous fp32
// error bound ~2e-2 << 0.0625); else block-uniform fp64 rerun (exact argmax,
// matches np reference — absmax 0.0 in rounds 1-4).

#define SR_F 16000.0f
#define HOP 256
#define FRAME_LEN 512
#define PAD 256
#define T_LEN 163840
#define N_FRAMES 641
#define MIN_PERIOD 32
#define N_LAGS 224
#define NGROUPS 14      // 16 lags per group; group g = tids 16g..16g+15
#define S_Q 144         // float4 slots (576 floats)
#define GAP_B 0.0625f

__device__ __forceinline__ int swz(int q) { return q ^ ((q >> 3) & 7); }

__global__ __launch_bounds__(256, 6) void f0_kernel(const float* __restrict__ wav,
                                                    float* __restrict__ out) {
    __shared__ float  s[S_Q * 4];   // swizzled frame (2304 B)
    __shared__ float  wv1[4], wv2[4];
    __shared__ int    wi1[4];
    __shared__ double dwv[4];
    __shared__ int    dwi[4];
    __shared__ int    need64;

    const int bf = blockIdx.x;                    // b * N_FRAMES + f
    const int b  = bf / N_FRAMES;
    const int f  = bf - b * N_FRAMES;
    const float* __restrict__ x = wav + (size_t)b * T_LEN;
    const int tid = threadIdx.x;
    const int base = f * HOP - PAD;

    // ---- stage frame into swizzled LDS ----
    if (f != 0 && f != N_FRAMES - 1) {
        // base = 256*(f-1): 16B-aligned, fully in-bounds -> float4 fast path
        if (tid < S_Q) {
            float4 v = make_float4(0.f, 0.f, 0.f, 0.f);
            if (tid < 128) v = ((const float4*)(x + base))[tid];
            ((float4*)s)[swz(tid)] = v;
        }
    } else {
        for (int t = tid; t < FRAME_LEN; t += 256) {
            int idx = base + t;
            if (idx < 0) idx = -idx;                       // reflect left
            if (idx >= T_LEN) idx = 2 * (T_LEN - 1) - idx; // reflect right
            s[(swz(t >> 2) << 2) | (t & 3)] = x[idx];
        }
        if (tid < (S_Q * 4 - FRAME_LEN)) {
            int t = FRAME_LEN + tid;
            s[(swz(t >> 2) << 2) | (t & 3)] = 0.0f;
        }
    }
    __syncthreads();

    const int g   = tid >> 4;                     // lag group, p0 = 32+16g
    const int seg = tid & 15;                     // t-segment (lane-local)
    const int p0  = MIN_PERIOD + (g << 4);
    const float4* s4 = (const float4*)s;

    // ---------------- fp32 MAC: 16 lags x 16 t per trip ----------------
    float acc[16];
    #pragma unroll
    for (int j = 0; j < 16; ++j) acc[j] = 0.0f;
    if (g < NGROUPS) {
        const int n16 = (FRAME_LEN - p0 + 15) >> 4;   // 30-g
        #pragma unroll
        for (int k = 0; k < 2; ++k) {
            const int ch = seg + (k << 4);
            if (ch < n16) {
                const int t  = ch << 4;
                const int qa = t >> 2;
                const int qw = (t + p0) >> 2;         // both 16B-exact
                float a[16], w[32];
                #pragma unroll
                for (int q = 0; q < 4; ++q) {
                    float4 v = s4[swz(qa + q)];
                    a[4*q+0]=v.x; a[4*q+1]=v.y; a[4*q+2]=v.z; a[4*q+3]=v.w;
                }
                #pragma unroll
                for (int q = 0; q < 8; ++q) {
                    float4 v = s4[swz(qw + q)];
                    w[4*q+0]=v.x; w[4*q+1]=v.y; w[4*q+2]=v.z; w[4*q+3]=v.w;
                }
                #pragma unroll
                for (int j = 0; j < 16; ++j) {
                    #pragma unroll
                    for (int i = 0; i < 16; ++i)
                        acc[j] = __builtin_fmaf(a[i], w[i + j], acc[j]);
                }
            }
        }
    }

    // ---- in-wave seg-sum butterfly: lane (g,seg) ends with lag 16g+seg ----
    float total;
    {
        float t8[8], t4[4], t2[2];
        int sel = seg & 1;
        #pragma unroll
        for (int i = 0; i < 8; ++i)
            t8[i] = acc[2*i + sel] + __shfl_xor(acc[2*i + (1 - sel)], 1);
        sel = (seg >> 1) & 1;
        #pragma unroll
        for (int i = 0; i < 4; ++i)
            t4[i] = t8[2*i + sel] + __shfl_xor(t8[2*i + (1 - sel)], 2);
        sel = (seg >> 2) & 1;
        #pragma unroll
        for (int i = 0; i < 2; ++i)
            t2[i] = t4[2*i + sel] + __shfl_xor(t4[2*i + (1 - sel)], 4);
        sel = (seg >> 3) & 1;
        total = t2[sel] + __shfl_xor(t2[1 - sel], 8);
    }

    // ---- 64-lane top-2 butterfly (first-index tie-break) ----
    float v1 = (tid < N_LAGS) ? total : -__builtin_inff();
    int   i1 = (tid < N_LAGS) ? tid : 0x7fffffff;
    float v2 = -__builtin_inff();
    #pragma unroll
    for (int m = 1; m < 64; m <<= 1) {
        float ov1 = __shfl_xor(v1, m);
        float ov2 = __shfl_xor(v2, m);
        int   oi1 = __shfl_xor(i1, m);
        bool take = (ov1 > v1) || (ov1 == v1 && oi1 < i1);
        float lose = take ? v1 : ov1;
        if (take) { v1 = ov1; i1 = oi1; }
        v2 = fmaxf(fmaxf(v2, ov2), lose);
    }

    const int wave = tid >> 6, lane = tid & 63;
    if (lane == 0) { wv1[wave] = v1; wv2[wave] = v2; wi1[wave] = i1; }
    __syncthreads();
    if (tid == 0) {
        float V1 = wv1[0], V2 = wv2[0];
        int   I1 = wi1[0];
        #pragma unroll
        for (int w = 1; w < 4; ++w) {
            float b1 = wv1[w]; int bi = wi1[w];
            bool take = (b1 > V1) || (b1 == V1 && bi < I1);
            float lose = take ? V1 : b1;
            if (take) { V1 = b1; I1 = bi; }
            V2 = fmaxf(fmaxf(V2, wv2[w]), lose);
        }
        int nd = (V1 - V2 <= GAP_B) ? 1 : 0;
        need64 = nd;
        if (!nd) {
            float period = (float)(I1 + MIN_PERIOD);
            float f0 = SR_F / (period + 1e-8f);
            out[bf] = fminf(fmaxf(f0, 50.0f), 500.0f);
        }
    }
    __syncthreads();

    if (need64) {
        // ------------- fp64 fallback (exact argmax), rare -------------
        double dacc[16];
        #pragma unroll
        for (int j = 0; j < 16; ++j) dacc[j] = 0.0;
        if (g < NGROUPS) {
            const int n16 = (FRAME_LEN - p0 + 15) >> 4;
            #pragma unroll
            for (int k = 0; k < 2; ++k) {
                const int ch = seg + (k << 4);
                if (ch < n16) {
                    const int t  = ch << 4;
                    const int qa = t >> 2;
                    const int qw = (t + p0) >> 2;
                    double a[16], w[32];
                    #pragma unroll
                    for (int q = 0; q < 4; ++q) {
                        float4 v = s4[swz(qa + q)];
                        a[4*q+0]=(double)v.x; a[4*q+1]=(double)v.y;
                        a[4*q+2]=(double)v.z; a[4*q+3]=(double)v.w;
                    }
                    #pragma unroll
                    for (int q = 0; q < 8; ++q) {
                        float4 v = s4[swz(qw + q)];
                        w[4*q+0]=(double)v.x; w[4*q+1]=(double)v.y;
                        w[4*q+2]=(double)v.z; w[4*q+3]=(double)v.w;
                    }
                    #pragma unroll
                    for (int j = 0; j < 16; ++j) {
                        #pragma unroll
                        for (int i = 0; i < 16; ++i)
                            dacc[j] = fma(a[i], w[i + j], dacc[j]);
                    }
                }
            }
        }
        double dtot;
        {
            double t8[8], t4[4], t2[2];
            int sel = seg & 1;
            #pragma unroll
            for (int i = 0; i < 8; ++i)
                t8[i] = dacc[2*i + sel] + __shfl_xor(dacc[2*i + (1 - sel)], 1);
            sel = (seg >> 1) & 1;
            #pragma unroll
            for (int i = 0; i < 4; ++i)
                t4[i] = t8[2*i + sel] + __shfl_xor(t8[2*i + (1 - sel)], 2);
            sel = (seg >> 2) & 1;
            #pragma unroll
            for (int i = 0; i < 2; ++i)
                t2[i] = t4[2*i + sel] + __shfl_xor(t4[2*i + (1 - sel)], 4);
            sel = (seg >> 3) & 1;
            dtot = t2[sel] + __shfl_xor(t2[1 - sel], 8);
        }
        double dv1 = (tid < N_LAGS) ? dtot : -__builtin_inf();
        int   di1 = (tid < N_LAGS) ? tid : 0x7fffffff;
        #pragma unroll
        for (int m = 1; m < 64; m <<= 1) {
            double o = __shfl_xor(dv1, m);
            int   oi = __shfl_xor(di1, m);
            if (o > dv1 || (o == dv1 && oi < di1)) { dv1 = o; di1 = oi; }
        }
        if (lane == 0) { dwv[wave] = dv1; dwi[wave] = di1; }
        __syncthreads();
        if (tid == 0) {
            double V = dwv[0]; int I = dwi[0];
            #pragma unroll
            for (int w = 1; w < 4; ++w) {
                if (dwv[w] > V || (dwv[w] == V && dwi[w] < I)) { V = dwv[w]; I = dwi[w]; }
            }
            float period = (float)(I + MIN_PERIOD);
            float f0 = SR_F / (period + 1e-8f);
            out[bf] = fminf(fmaxf(f0, 50.0f), 500.0f);
        }
    }
}

extern "C" void kernel_launch(void* const* d_in, const int* in_sizes, int n_in,
                              void* d_out, int out_size, void* d_ws, size_t ws_size,
                              hipStream_t stream) {
    const float* wav = (const float*)d_in[0]; // (64, 1, 163840) fp32
    float* out = (float*)d_out;               // (64, 641) fp32
    const int n_blocks = 64 * N_FRAMES;       // 41024
    f0_kernel<<<n_blocks, 256, 0, stream>>>(wav, out);
}

// Round 6
// 237.910 us; speedup vs baseline: 2.8718x; 2.8718x over previous
//
#include <hip/hip_runtime.h>

// F0 via autocorrelation argmax — round 6: register-safe shuffle reduction.
//   SR=16000, HOP=256, FRAME_LEN=512, pad=256, T=163840, B=64, n_frames=641
//   lags p in [32,256), 224 lags. Per-frame normalization is a positive
//   scalar -> argmax of RAW autocorrelation equals reference argmax.
//
// Round-5 lesson (counters): FETCH 441MB / WRITE 2.1GB, VGPR=40 -> the
// butterfly's RUNTIME-VARIABLE array indices (acc[2*i+sel]) demoted all
// tile arrays to scratch; every FMA operand round-tripped through HBM.
// Fix: constant indices + scalar selects (v_cndmask), same balanced-tree
// arithmetic, arrays stay in VGPRs. fp64 fallback keeps its window in fp32
// regs and converts per-use to stay under the VGPR cap.
//
// Numerics: fp32 accepted iff top1-top2 gap > GAP_B (rigorous fp32 error
// bound ~2e-2 << 0.0625); else block-uniform fp64 rerun -> exact argmax.

#define SR_F 16000.0f
#define HOP 256
#define FRAME_LEN 512
#define PAD 256
#define T_LEN 163840
#define N_FRAMES 641
#define MIN_PERIOD 32
#define N_LAGS 224
#define NGROUPS 14      // 16 lags per group; group g = tids 16g..16g+15
#define S_Q 144         // float4 slots (576 floats)
#define GAP_B 0.0625f

__device__ __forceinline__ int swz(int q) { return q ^ ((q >> 3) & 7); }

__global__ __launch_bounds__(256, 4) void f0_kernel(const float* __restrict__ wav,
                                                    float* __restrict__ out) {
    __shared__ float  s[S_Q * 4];   // swizzled frame (2304 B)
    __shared__ float  wv1[4], wv2[4];
    __shared__ int    wi1[4];
    __shared__ double dwv[4];
    __shared__ int    dwi[4];
    __shared__ int    need64;

    const int bf = blockIdx.x;                    // b * N_FRAMES + f
    const int b  = bf / N_FRAMES;
    const int f  = bf - b * N_FRAMES;
    const float* __restrict__ x = wav + (size_t)b * T_LEN;
    const int tid = threadIdx.x;
    const int base = f * HOP - PAD;

    // ---- stage frame into swizzled LDS ----
    if (f != 0 && f != N_FRAMES - 1) {
        // base = 256*(f-1): 16B-aligned, fully in-bounds -> float4 fast path
        if (tid < S_Q) {
            float4 v = make_float4(0.f, 0.f, 0.f, 0.f);
            if (tid < 128) v = ((const float4*)(x + base))[tid];
            ((float4*)s)[swz(tid)] = v;
        }
    } else {
        for (int t = tid; t < FRAME_LEN; t += 256) {
            int idx = base + t;
            if (idx < 0) idx = -idx;                       // reflect left
            if (idx >= T_LEN) idx = 2 * (T_LEN - 1) - idx; // reflect right
            s[(swz(t >> 2) << 2) | (t & 3)] = x[idx];
        }
        if (tid < (S_Q * 4 - FRAME_LEN)) {
            int t = FRAME_LEN + tid;
            s[(swz(t >> 2) << 2) | (t & 3)] = 0.0f;
        }
    }
    __syncthreads();

    const int g   = tid >> 4;                     // lag group, p0 = 32+16g
    const int seg = tid & 15;                     // t-segment (lane-local)
    const int p0  = MIN_PERIOD + (g << 4);
    const float4* s4 = (const float4*)s;

    // ---------------- fp32 MAC: 16 lags x 16 t per trip ----------------
    float acc[16];
    #pragma unroll
    for (int j = 0; j < 16; ++j) acc[j] = 0.0f;
    if (g < NGROUPS) {
        const int n16 = (FRAME_LEN - p0 + 15) >> 4;   // 30-g
        #pragma unroll
        for (int k = 0; k < 2; ++k) {
            const int ch = seg + (k << 4);
            if (ch < n16) {
                const int t  = ch << 4;
                const int qa = t >> 2;
                const int qw = (t + p0) >> 2;         // both 16B-exact
                float a[16], w[32];
                #pragma unroll
                for (int q = 0; q < 4; ++q) {
                    float4 v = s4[swz(qa + q)];
                    a[4*q+0]=v.x; a[4*q+1]=v.y; a[4*q+2]=v.z; a[4*q+3]=v.w;
                }
                #pragma unroll
                for (int q = 0; q < 8; ++q) {
                    float4 v = s4[swz(qw + q)];
                    w[4*q+0]=v.x; w[4*q+1]=v.y; w[4*q+2]=v.z; w[4*q+3]=v.w;
                }
                #pragma unroll
                for (int j = 0; j < 16; ++j) {
                    #pragma unroll
                    for (int i = 0; i < 16; ++i)
                        acc[j] = __builtin_fmaf(a[i], w[i + j], acc[j]);
                }
            }
        }
    }

    // ---- in-wave seg-sum butterfly (constant indices + selects) ----
    // After step d, value i belongs to lag 16g + (low d bits of seg) + i<<d.
    float total;
    {
        const bool s0 = (seg & 1), s1 = (seg & 2), s2 = (seg & 4), s3 = (seg & 8);
        float t8[8], t4[4], t2[2];
        #pragma unroll
        for (int i = 0; i < 8; ++i) {
            float lo = acc[2*i], hi = acc[2*i+1];
            float keep = s0 ? hi : lo, send = s0 ? lo : hi;
            t8[i] = keep + __shfl_xor(send, 1);
        }
        #pragma unroll
        for (int i = 0; i < 4; ++i) {
            float lo = t8[2*i], hi = t8[2*i+1];
            float keep = s1 ? hi : lo, send = s1 ? lo : hi;
            t4[i] = keep + __shfl_xor(send, 2);
        }
        #pragma unroll
        for (int i = 0; i < 2; ++i) {
            float lo = t4[2*i], hi = t4[2*i+1];
            float keep = s2 ? hi : lo, send = s2 ? lo : hi;
            t2[i] = keep + __shfl_xor(send, 4);
        }
        {
            float lo = t2[0], hi = t2[1];
            float keep = s3 ? hi : lo, send = s3 ? lo : hi;
            total = keep + __shfl_xor(send, 8);
        }
    }

    // ---- 64-lane top-2 butterfly (first-index tie-break) ----
    float v1 = (tid < N_LAGS) ? total : -__builtin_inff();
    int   i1 = (tid < N_LAGS) ? tid : 0x7fffffff;
    float v2 = -__builtin_inff();
    #pragma unroll
    for (int m = 1; m < 64; m <<= 1) {
        float ov1 = __shfl_xor(v1, m);
        float ov2 = __shfl_xor(v2, m);
        int   oi1 = __shfl_xor(i1, m);
        bool take = (ov1 > v1) || (ov1 == v1 && oi1 < i1);
        float lose = take ? v1 : ov1;
        if (take) { v1 = ov1; i1 = oi1; }
        v2 = fmaxf(fmaxf(v2, ov2), lose);
    }

    const int wave = tid >> 6, lane = tid & 63;
    if (lane == 0) { wv1[wave] = v1; wv2[wave] = v2; wi1[wave] = i1; }
    __syncthreads();
    if (tid == 0) {
        float V1 = wv1[0], V2 = wv2[0];
        int   I1 = wi1[0];
        #pragma unroll
        for (int w = 1; w < 4; ++w) {
            float b1 = wv1[w]; int bi = wi1[w];
            bool take = (b1 > V1) || (b1 == V1 && bi < I1);
            float lose = take ? V1 : b1;
            if (take) { V1 = b1; I1 = bi; }
            V2 = fmaxf(fmaxf(V2, wv2[w]), lose);
        }
        int nd = (V1 - V2 <= GAP_B) ? 1 : 0;
        need64 = nd;
        if (!nd) {
            float period = (float)(I1 + MIN_PERIOD);
            float f0 = SR_F / (period + 1e-8f);
            out[bf] = fminf(fmaxf(f0, 50.0f), 500.0f);
        }
    }
    __syncthreads();

    if (need64) {
        // ---- fp64 fallback (exact argmax), rare; fp32 regs, cvt per use ----
        double dacc[16];
        #pragma unroll
        for (int j = 0; j < 16; ++j) dacc[j] = 0.0;
        if (g < NGROUPS) {
            const int n16 = (FRAME_LEN - p0 + 15) >> 4;
            #pragma unroll
            for (int k = 0; k < 2; ++k) {
                const int ch = seg + (k << 4);
                if (ch < n16) {
                    const int t  = ch << 4;
                    const int qa = t >> 2;
                    const int qw = (t + p0) >> 2;
                    float a[16], w[32];
                    #pragma unroll
                    for (int q = 0; q < 4; ++q) {
                        float4 v = s4[swz(qa + q)];
                        a[4*q+0]=v.x; a[4*q+1]=v.y; a[4*q+2]=v.z; a[4*q+3]=v.w;
                    }
                    #pragma unroll
                    for (int q = 0; q < 8; ++q) {
                        float4 v = s4[swz(qw + q)];
                        w[4*q+0]=v.x; w[4*q+1]=v.y; w[4*q+2]=v.z; w[4*q+3]=v.w;
                    }
                    #pragma unroll
                    for (int j = 0; j < 16; ++j) {
                        #pragma unroll
                        for (int i = 0; i < 16; ++i)
                            dacc[j] = fma((double)a[i], (double)w[i + j], dacc[j]);
                    }
                }
            }
        }
        double dtot;
        {
            const bool s0 = (seg & 1), s1 = (seg & 2), s2 = (seg & 4), s3 = (seg & 8);
            double t8[8], t4[4], t2[2];
            #pragma unroll
            for (int i = 0; i < 8; ++i) {
                double lo = dacc[2*i], hi = dacc[2*i+1];
                double keep = s0 ? hi : lo, send = s0 ? lo : hi;
                t8[i] = keep + __shfl_xor(send, 1);
            }
            #pragma unroll
            for (int i = 0; i < 4; ++i) {
                double lo = t8[2*i], hi = t8[2*i+1];
                double keep = s1 ? hi : lo, send = s1 ? lo : hi;
                t4[i] = keep + __shfl_xor(send, 2);
            }
            #pragma unroll
            for (int i = 0; i < 2; ++i) {
                double lo = t4[2*i], hi = t4[2*i+1];
                double keep = s2 ? hi : lo, send = s2 ? lo : hi;
                t2[i] = keep + __shfl_xor(send, 4);
            }
            {
                double lo = t2[0], hi = t2[1];
                double keep = s3 ? hi : lo, send = s3 ? lo : hi;
                dtot = keep + __shfl_xor(send, 8);
            }
        }
        double dv1 = (tid < N_LAGS) ? dtot : -__builtin_inf();
        int   di1 = (tid < N_LAGS) ? tid : 0x7fffffff;
        #pragma unroll
        for (int m = 1; m < 64; m <<= 1) {
            double o = __shfl_xor(dv1, m);
            int   oi = __shfl_xor(di1, m);
            if (o > dv1 || (o == dv1 && oi < di1)) { dv1 = o; di1 = oi; }
        }
        if (lane == 0) { dwv[wave] = dv1; dwi[wave] = di1; }
        __syncthreads();
        if (tid == 0) {
            double V = dwv[0]; int I = dwi[0];
            #pragma unroll
            for (int w = 1; w < 4; ++w) {
                if (dwv[w] > V || (dwv[w] == V && dwi[w] < I)) { V = dwv[w]; I = dwi[w]; }
            }
            float period = (float)(I + MIN_PERIOD);
            float f0 = SR_F / (period + 1e-8f);
            out[bf] = fminf(fmaxf(f0, 50.0f), 500.0f);
        }
    }
}

extern "C" void kernel_launch(void* const* d_in, const int* in_sizes, int n_in,
                              void* d_out, int out_size, void* d_ws, size_t ws_size,
                              hipStream_t stream) {
    const float* wav = (const float*)d_in[0]; // (64, 1, 163840) fp32
    float* out = (float*)d_out;               // (64, 641) fp32
    const int n_blocks = 64 * N_FRAMES;       // 41024
    f0_kernel<<<n_blocks, 256, 0, stream>>>(wav, out);
}

// Round 7
// 214.527 us; speedup vs baseline: 3.1848x; 1.1090x over previous
//
#include <hip/hip_runtime.h>

// F0 via autocorrelation argmax — round 7: wave-per-frame, barrier-free.
//   SR=16000, HOP=256, FRAME_LEN=512, pad=256, T=163840, B=64, n_frames=641
//   lags p in [32,256), 224 lags. Per-frame normalization is a positive
//   scalar -> argmax of RAW autocorrelation equals reference argmax.
//
// Round-6 lesson (counters): per-CU LDS pipe (~2400 cyc/frame: 96 b128
// reads, 4 butterflies, conflicts) + 3 __syncthreads convoys at low
// occupancy bound the kernel, not FMA issue (floor 43 us).
// Fix: each of the 4 waves owns one WHOLE frame in a private LDS slice ->
// no barriers at all; 4 lag-group rounds per wave (16-lag x 16-t tile,
// seg-sum butterfly per round); a-reads are 4-way broadcasts; top-2 needs
// one 64-lane butterfly; gap test is wave-uniform (no LDS flag).
//
// Numerics: fp32 accepted iff top1-top2 gap > GAP_B (rigorous fp32 error
// bound ~2e-2 << 0.0625); else per-wave fp64 rerun -> exact argmax
// (absmax 0.0 in rounds 1-6).

#define SR_F 16000.0f
#define HOP 256
#define FRAME_LEN 512
#define PAD 256
#define T_LEN 163840
#define N_FRAMES 641
#define MIN_PERIOD 32
#define N_LAGS 224
#define S_Q 144         // float4 slots per frame slice (576 floats)
#define GAP_B 0.0625f
#define FPB 4           // frames per block = waves per block

__device__ __forceinline__ int swz(int q) { return q ^ ((q >> 3) & 7); }

__global__ __launch_bounds__(256, 4) void f0_kernel(const float* __restrict__ wav,
                                                    float* __restrict__ out) {
    __shared__ float s[FPB * S_Q * 4];   // 9216 B: one swizzled slice per wave

    const int tid  = threadIdx.x;
    const int wv   = tid >> 6;
    const int lane = tid & 63;
    const int bf   = blockIdx.x * FPB + wv;       // 10256*4 == 41024 exactly
    const int b    = bf / N_FRAMES;
    const int f    = bf - b * N_FRAMES;
    const float* __restrict__ x = wav + (size_t)b * T_LEN;
    float* sw = s + wv * (S_Q * 4);
    const float4* s4 = (const float4*)sw;
    float4* s4w = (float4*)sw;
    const int base = f * HOP - PAD;

    // ---- stage frame into this wave's swizzled slice (no barrier) ----
    if (f != 0 && f != N_FRAMES - 1) {
        const float4* g4 = (const float4*)(x + base);  // 16B-aligned, in-bounds
        s4w[swz(lane)]      = g4[lane];
        s4w[swz(lane + 64)] = g4[lane + 64];
        if (lane < 16) s4w[swz(lane + 128)] = make_float4(0.f, 0.f, 0.f, 0.f);
    } else {
        for (int t = lane; t < FRAME_LEN; t += 64) {
            int idx = base + t;
            if (idx < 0) idx = -idx;                       // reflect left
            if (idx >= T_LEN) idx = 2 * (T_LEN - 1) - idx; // reflect right
            sw[(swz(t >> 2) << 2) | (t & 3)] = x[idx];
        }
        {   // floats 512..575 -> zero (exactly one per lane)
            int t = FRAME_LEN + lane;
            sw[(swz(t >> 2) << 2) | (t & 3)] = 0.0f;
        }
    }
    __threadfence_block();   // order ds_write -> ds_read (waitcnt, no barrier)

    const int q   = lane >> 4;            // quarter = lag group within round
    const int seg = lane & 15;            // t-segment
    const bool s0 = (seg & 1), s1 = (seg & 2), s2 = (seg & 4), s3 = (seg & 8);

    // ---------------- fp32: 4 rounds of 16 lags x 16 t tiles ----------------
    float tot[4];
    #pragma unroll
    for (int r = 0; r < 4; ++r) {
        const int g  = (r << 2) + q;                   // lag group 0..15 (14 real)
        const int p0 = MIN_PERIOD + (g << 4);
        float acc[16];
        #pragma unroll
        for (int j = 0; j < 16; ++j) acc[j] = 0.0f;
        if (g < 14) {
            const int n16 = (FRAME_LEN - p0 + 15) >> 4;    // 30 - g
            #pragma unroll
            for (int k = 0; k < 2; ++k) {
                const int ch = seg + (k << 4);
                if (ch < n16) {
                    const int t  = ch << 4;
                    const int qa = t >> 2;
                    const int qw = (t + p0) >> 2;          // 16B-exact
                    float a[16], w[32];
                    #pragma unroll
                    for (int u = 0; u < 4; ++u) {
                        float4 v = s4[swz(qa + u)];        // 4-way broadcast
                        a[4*u+0]=v.x; a[4*u+1]=v.y; a[4*u+2]=v.z; a[4*u+3]=v.w;
                    }
                    #pragma unroll
                    for (int u = 0; u < 8; ++u) {
                        float4 v = s4[swz(qw + u)];
                        w[4*u+0]=v.x; w[4*u+1]=v.y; w[4*u+2]=v.z; w[4*u+3]=v.w;
                    }
                    #pragma unroll
                    for (int j = 0; j < 16; ++j) {
                        #pragma unroll
                        for (int i = 0; i < 16; ++i)
                            acc[j] = __builtin_fmaf(a[i], w[i + j], acc[j]);
                    }
                }
            }
        }
        // seg-sum butterfly (constant indices + selects); lanes mix only
        // within their 16-lane quarter (masks 1,2,4,8).
        float t8[8], t4[4], t2[2], total;
        #pragma unroll
        for (int i = 0; i < 8; ++i) {
            float lo = acc[2*i], hi = acc[2*i+1];
            float keep = s0 ? hi : lo, send = s0 ? lo : hi;
            t8[i] = keep + __shfl_xor(send, 1);
        }
        #pragma unroll
        for (int i = 0; i < 4; ++i) {
            float lo = t8[2*i], hi = t8[2*i+1];
            float keep = s1 ? hi : lo, send = s1 ? lo : hi;
            t4[i] = keep + __shfl_xor(send, 2);
        }
        #pragma unroll
        for (int i = 0; i < 2; ++i) {
            float lo = t4[2*i], hi = t4[2*i+1];
            float keep = s2 ? hi : lo, send = s2 ? lo : hi;
            t2[i] = keep + __shfl_xor(send, 4);
        }
        {
            float lo = t2[0], hi = t2[1];
            float keep = s3 ? hi : lo, send = s3 ? lo : hi;
            total = keep + __shfl_xor(send, 8);
        }
        // lane now holds lag index 64r + lane (if valid)
        tot[r] = ((r << 6) + lane < N_LAGS) ? total : -__builtin_inff();
    }

    // ---- per-lane top-2 over its 4 lags (increasing lag id -> strict >) ----
    float v1 = tot[0], v2 = -__builtin_inff();
    int   i1 = lane;
    #pragma unroll
    for (int r = 1; r < 4; ++r) {
        float c = tot[r];
        bool take = (c > v1);
        float lose = take ? v1 : c;
        if (take) { v1 = c; i1 = (r << 6) + lane; }
        v2 = fmaxf(v2, lose);
    }

    // ---- 64-lane top-2 butterfly (first-index tie-break) ----
    #pragma unroll
    for (int m = 1; m < 64; m <<= 1) {
        float ov1 = __shfl_xor(v1, m);
        float ov2 = __shfl_xor(v2, m);
        int   oi1 = __shfl_xor(i1, m);
        bool take = (ov1 > v1) || (ov1 == v1 && oi1 < i1);
        float lose = take ? v1 : ov1;
        if (take) { v1 = ov1; i1 = oi1; }
        v2 = fmaxf(fmaxf(v2, ov2), lose);
    }
    // every lane now has V1/V2/I1 -> wave-uniform branch, no LDS, no barrier

    if (v1 - v2 > GAP_B) {
        if (lane == 0) {
            float period = (float)(i1 + MIN_PERIOD);
            float f0 = SR_F / (period + 1e-8f);
            out[bf] = fminf(fmaxf(f0, 50.0f), 500.0f);
        }
    } else {
        // ---- fp64 fallback (exact argmax), rare; fp32 regs, cvt per use ----
        double dtot[4];
        #pragma unroll
        for (int r = 0; r < 4; ++r) {
            const int g  = (r << 2) + q;
            const int p0 = MIN_PERIOD + (g << 4);
            double dacc[16];
            #pragma unroll
            for (int j = 0; j < 16; ++j) dacc[j] = 0.0;
            if (g < 14) {
                const int n16 = (FRAME_LEN - p0 + 15) >> 4;
                #pragma unroll
                for (int k = 0; k < 2; ++k) {
                    const int ch = seg + (k << 4);
                    if (ch < n16) {
                        const int t  = ch << 4;
                        const int qa = t >> 2;
                        const int qw = (t + p0) >> 2;
                        float a[16], w[32];
                        #pragma unroll
                        for (int u = 0; u < 4; ++u) {
                            float4 v = s4[swz(qa + u)];
                            a[4*u+0]=v.x; a[4*u+1]=v.y; a[4*u+2]=v.z; a[4*u+3]=v.w;
                        }
                        #pragma unroll
                        for (int u = 0; u < 8; ++u) {
                            float4 v = s4[swz(qw + u)];
                            w[4*u+0]=v.x; w[4*u+1]=v.y; w[4*u+2]=v.z; w[4*u+3]=v.w;
                        }
                        #pragma unroll
                        for (int j = 0; j < 16; ++j) {
                            #pragma unroll
                            for (int i = 0; i < 16; ++i)
                                dacc[j] = fma((double)a[i], (double)w[i + j], dacc[j]);
                        }
                    }
                }
            }
            double u8[8], u4[4], u2[2], dtotal;
            #pragma unroll
            for (int i = 0; i < 8; ++i) {
                double lo = dacc[2*i], hi = dacc[2*i+1];
                double keep = s0 ? hi : lo, send = s0 ? lo : hi;
                u8[i] = keep + __shfl_xor(send, 1);
            }
            #pragma unroll
            for (int i = 0; i < 4; ++i) {
                double lo = u8[2*i], hi = u8[2*i+1];
                double keep = s1 ? hi : lo, send = s1 ? lo : hi;
                u4[i] = keep + __shfl_xor(send, 2);
            }
            #pragma unroll
            for (int i = 0; i < 2; ++i) {
                double lo = u4[2*i], hi = u4[2*i+1];
                double keep = s2 ? hi : lo, send = s2 ? lo : hi;
                u2[i] = keep + __shfl_xor(send, 4);
            }
            {
                double lo = u2[0], hi = u2[1];
                double keep = s3 ? hi : lo, send = s3 ? lo : hi;
                dtotal = keep + __shfl_xor(send, 8);
            }
            dtot[r] = ((r << 6) + lane < N_LAGS) ? dtotal : -__builtin_inf();
        }
        double dv1 = dtot[0];
        int    di1 = lane;
        #pragma unroll
        for (int r = 1; r < 4; ++r) {
            double c = dtot[r];
            if (c > dv1) { dv1 = c; di1 = (r << 6) + lane; }
        }
        #pragma unroll
        for (int m = 1; m < 64; m <<= 1) {
            double o = __shfl_xor(dv1, m);
            int   oi = __shfl_xor(di1, m);
            if (o > dv1 || (o == dv1 && oi < di1)) { dv1 = o; di1 = oi; }
        }
        if (lane == 0) {
            float period = (float)(di1 + MIN_PERIOD);
            float f0 = SR_F / (period + 1e-8f);
            out[bf] = fminf(fmaxf(f0, 50.0f), 500.0f);
        }
    }
}

extern "C" void kernel_launch(void* const* d_in, const int* in_sizes, int n_in,
                              void* d_out, int out_size, void* d_ws, size_t ws_size,
                              hipStream_t stream) {
    const float* wav = (const float*)d_in[0]; // (64, 1, 163840) fp32
    float* out = (float*)d_out;               // (64, 641) fp32
    const int n_blocks = (64 * N_FRAMES) / FPB;   // 10256
    f0_kernel<<<n_blocks, 256, 0, stream>>>(wav, out);
}

// Round 8
// 150.175 us; speedup vs baseline: 4.5496x; 1.4285x over previous
//
#include <hip/hip_runtime.h>

// F0 via autocorrelation argmax — round 8: MFMA reformulation.
//   SR=16000, HOP=256, FRAME_LEN=512, pad=256, T=163840, B=64, n_frames=641
//   lags p in [32,256). Normalization is a positive per-frame scalar ->
//   argmax of RAW autocorrelation equals reference argmax.
//
// GEMM cast (per frame, y = frame zero-extended outside [0,512)):
//   A[m,k] = y[k-16m], B[k,n] = y[k+32+n]  =>  D[m,n] = AC[32+16m+n]
//   => 16 chained mfma_f32_16x16x32_f16 (K=512) give all 224 lags.
// LDS: y staged in f16 with a 240-elem zero margin, TWO parity copies
// (ye natural, yo shifted by one element) so B-frags (per-lane +n shift)
// are 4 aligned dword reads; A-frags (shift 16m) are aligned b128 reads.
//
// 3-tier numerics: f16 MFMA error <= 2^-10*Q (Q=frame energy, Cauchy-
// Schwarz) + eps; accept if top2 gap > 2E. Else fp32 register-tile path
// (proven rounds 3-7, gap 0.0625). Else fp64 (exact argmax).

#define SR_F 16000.0f
#define HOP 256
#define FRAME_LEN 512
#define PAD 256
#define T_LEN 163840
#define N_FRAMES 641
#define MIN_PERIOD 32
#define N_LAGS 224
#define FPB 4
#define GAP_B32 0.0625f

typedef _Float16 half8 __attribute__((ext_vector_type(8)));
typedef float floatx4 __attribute__((ext_vector_type(4)));

__device__ __forceinline__ int swz(int q) { return q ^ ((q >> 3) & 7); }

__device__ __forceinline__ unsigned int pkh(float a, float b) {
    unsigned short ha = __builtin_bit_cast(unsigned short, (_Float16)a);
    unsigned short hb = __builtin_bit_cast(unsigned short, (_Float16)b);
    return (unsigned int)ha | ((unsigned int)hb << 16);
}

__global__ __launch_bounds__(256, 4) void f0_kernel(const float* __restrict__ wav,
                                                    float* __restrict__ out) {
    // per-wave slice: ye[400 dwords] + yo[400 dwords] = 3200 B (f16, dword-packed)
    __shared__ unsigned int yw[FPB][800];

    const int tid  = threadIdx.x;
    const int wv   = tid >> 6;
    const int lane = tid & 63;
    const int bf   = blockIdx.x * FPB + wv;       // 10256*4 == 41024
    const int b    = bf / N_FRAMES;
    const int f    = bf - b * N_FRAMES;
    const float* __restrict__ x = wav + (size_t)b * T_LEN;
    unsigned int* ye = yw[wv];
    unsigned int* yo = ye + 400;
    const int base = f * HOP - PAD;

    // ---- zero margins: dwords [0,120) and [375,400) of both copies ----
    ye[lane] = 0u; yo[lane] = 0u;                 // 0..63
    if (lane < 56) { ye[64 + lane] = 0u; yo[64 + lane] = 0u; }   // 64..119
    if (lane < 25) { ye[375 + lane] = 0u; yo[375 + lane] = 0u; } // 375..399

    float qen = 0.0f;   // frame energy (fp32)
    if (f != 0 && f != N_FRAMES - 1) {
        const float4* g4 = (const float4*)(x + base);  // 1KB-aligned, in-bounds
        float4 c1 = g4[lane];
        float4 c2 = g4[lane + 64];
        qen = c1.x*c1.x + c1.y*c1.y + c1.z*c1.z + c1.w*c1.w
            + c2.x*c2.x + c2.y*c2.y + c2.z*c2.z + c2.w*c2.w;
        unsigned int u10 = pkh(c1.x, c1.y), u11 = pkh(c1.z, c1.w);
        unsigned int u20 = pkh(c2.x, c2.y), u21 = pkh(c2.z, c2.w);
        // ye: lane owns elements 4L..4L+3 and 4L+256..4L+259 (dwords 2L..)
        ye[120 + 2*lane] = u10;  ye[121 + 2*lane] = u11;
        ye[248 + 2*lane] = u20;  ye[249 + 2*lane] = u21;
        // yo dword v = (d_v>>16)|(d_{v+1}<<16); neighbors via shuffles
        unsigned int a  = __shfl(u10, (lane + 1) & 63);
        unsigned int bb = __shfl(u20, (lane + 1) & 63);
        unsigned int n1 = (lane == 63) ? bb : a;
        unsigned int n2 = (lane == 63) ? 0u : bb;
        yo[120 + 2*lane] = (u10 >> 16) | (u11 << 16);
        yo[121 + 2*lane] = (u11 >> 16) | (n1 << 16);
        yo[248 + 2*lane] = (u20 >> 16) | (u21 << 16);
        yo[249 + 2*lane] = (u21 >> 16) | (n2 << 16);
        if (lane == 0) yo[119] = u10 << 16;       // {Y[-1]=0, Y[0]}
    } else {
        for (int t = lane; t < FRAME_LEN; t += 64) {
            int idx = base + t;
            if (idx < 0) idx = -idx;
            if (idx >= T_LEN) idx = 2 * (T_LEN - 1) - idx;
            float v = x[idx];
            qen = __builtin_fmaf(v, v, qen);
            unsigned short h = __builtin_bit_cast(unsigned short, (_Float16)v);
            ((unsigned short*)ye)[240 + t] = h;   // ye elem 240+t = Y[t]
            ((unsigned short*)yo)[239 + t] = h;   // yo elem e = Y[e-239]
        }
    }
    __threadfence_block();

    // Q reduction (all lanes end with full frame energy)
    #pragma unroll
    for (int m = 1; m < 64; m <<= 1) qen += __shfl_xor(qen, m);

    // ---------------- MFMA: 16 steps of 16x16x32 f16 ----------------
    const int qd = lane >> 4;       // quad
    const int nn = lane & 15;       // = m for A-frag, n for B-frag
    const int par = nn & 1;
    const unsigned int* yb = par ? yo : ye;
    const int wA0 = 120 + 4*qd - 8*nn;                 // dword base, step +16
    const int wB0 = 136 + 4*qd + ((nn - par) >> 1);    // dword base, step +16

    floatx4 acc = {0.f, 0.f, 0.f, 0.f};
    #pragma unroll
    for (int c = 0; c < 16; ++c) {
        uint4 au = *(const uint4*)(ye + (wA0 + 16*c));     // aligned b128
        const unsigned int* pb = yb + (wB0 + 16*c);
        uint4 bu;
        bu.x = pb[0]; bu.y = pb[1]; bu.z = pb[2]; bu.w = pb[3];
        half8 af = __builtin_bit_cast(half8, au);
        half8 bfv = __builtin_bit_cast(half8, bu);
        acc = __builtin_amdgcn_mfma_f32_16x16x32_f16(af, bfv, acc, 0, 0, 0);
    }

    // ---- per-lane top-2 over acc[r]: lag idx = 64*qd + 16*r + nn ----
    // valid iff m = 4*qd + r < 14; r ascending => lag ascending (tie=first)
    float v1 = acc[0];              // m = 4*qd <= 12 always valid
    int   i1 = 64*qd + nn;
    float v2 = -__builtin_inff();
    #pragma unroll
    for (int r = 1; r < 4; ++r) {
        float cv = (4*qd + r < 14) ? acc[r] : -__builtin_inff();
        bool take = (cv > v1);
        float lose = take ? v1 : cv;
        if (take) { v1 = cv; i1 = 64*qd + 16*r + nn; }
        v2 = fmaxf(v2, lose);
    }
    // ---- 64-lane top-2 butterfly (first-index tie-break) ----
    #pragma unroll
    for (int m = 1; m < 64; m <<= 1) {
        float ov1 = __shfl_xor(v1, m);
        float ov2 = __shfl_xor(v2, m);
        int   oi1 = __shfl_xor(i1, m);
        bool take = (ov1 > v1) || (ov1 == v1 && oi1 < i1);
        float lose = take ? v1 : ov1;
        if (take) { v1 = ov1; i1 = oi1; }
        v2 = fmaxf(fmaxf(v2, ov2), lose);
    }

    // rigorous f16 error bound: E = 2^-10 * Q + slack
    const float E1 = 9.765625e-4f * qen + 0.05f;
    if (v1 - v2 > 2.0f * E1) {
        if (lane == 0) {
            float period = (float)(i1 + MIN_PERIOD);
            float f0 = SR_F / (period + 1e-8f);
            out[bf] = fminf(fmaxf(f0, 50.0f), 500.0f);
        }
        return;
    }

    // =============== tier-2: fp32 register tile (rounds 3-7) ===============
    // restage fp32 swizzled frame over this wave's slice (576 floats < 800 dw)
    float* sw = (float*)ye;
    if (f != 0 && f != N_FRAMES - 1) {
        const float4* g4 = (const float4*)(x + base);
        ((float4*)sw)[swz(lane)]      = g4[lane];
        ((float4*)sw)[swz(lane + 64)] = g4[lane + 64];
        if (lane < 16) ((float4*)sw)[swz(lane + 128)] = make_float4(0.f,0.f,0.f,0.f);
    } else {
        for (int t = lane; t < FRAME_LEN; t += 64) {
            int idx = base + t;
            if (idx < 0) idx = -idx;
            if (idx >= T_LEN) idx = 2 * (T_LEN - 1) - idx;
            sw[(swz(t >> 2) << 2) | (t & 3)] = x[idx];
        }
        int t = FRAME_LEN + lane;
        sw[(swz(t >> 2) << 2) | (t & 3)] = 0.0f;
    }
    __threadfence_block();

    const float4* s4 = (const float4*)sw;
    const int seg = lane & 15;
    const bool s0 = (seg & 1), s1 = (seg & 2), s2 = (seg & 4), s3 = (seg & 8);

    float tot[4];
    #pragma unroll
    for (int r = 0; r < 4; ++r) {
        const int g  = (r << 2) + qd;
        const int p0 = MIN_PERIOD + (g << 4);
        float acc2[16];
        #pragma unroll
        for (int j = 0; j < 16; ++j) acc2[j] = 0.0f;
        if (g < 14) {
            const int n16 = (FRAME_LEN - p0 + 15) >> 4;
            #pragma unroll
            for (int k = 0; k < 2; ++k) {
                const int ch = seg + (k << 4);
                if (ch < n16) {
                    const int t  = ch << 4;
                    const int qa = t >> 2;
                    const int qw = (t + p0) >> 2;
                    float a[16], w[32];
                    #pragma unroll
                    for (int u = 0; u < 4; ++u) {
                        float4 v = s4[swz(qa + u)];
                        a[4*u+0]=v.x; a[4*u+1]=v.y; a[4*u+2]=v.z; a[4*u+3]=v.w;
                    }
                    #pragma unroll
                    for (int u = 0; u < 8; ++u) {
                        float4 v = s4[swz(qw + u)];
                        w[4*u+0]=v.x; w[4*u+1]=v.y; w[4*u+2]=v.z; w[4*u+3]=v.w;
                    }
                    #pragma unroll
                    for (int j = 0; j < 16; ++j) {
                        #pragma unroll
                        for (int i = 0; i < 16; ++i)
                            acc2[j] = __builtin_fmaf(a[i], w[i + j], acc2[j]);
                    }
                }
            }
        }
        float t8[8], t4[4], t2[2], total;
        #pragma unroll
        for (int i = 0; i < 8; ++i) {
            float lo = acc2[2*i], hi = acc2[2*i+1];
            float keep = s0 ? hi : lo, send = s0 ? lo : hi;
            t8[i] = keep + __shfl_xor(send, 1);
        }
        #pragma unroll
        for (int i = 0; i < 4; ++i) {
            float lo = t8[2*i], hi = t8[2*i+1];
            float keep = s1 ? hi : lo, send = s1 ? lo : hi;
            t4[i] = keep + __shfl_xor(send, 2);
        }
        #pragma unroll
        for (int i = 0; i < 2; ++i) {
            float lo = t4[2*i], hi = t4[2*i+1];
            float keep = s2 ? hi : lo, send = s2 ? lo : hi;
            t2[i] = keep + __shfl_xor(send, 4);
        }
        {
            float lo = t2[0], hi = t2[1];
            float keep = s3 ? hi : lo, send = s3 ? lo : hi;
            total = keep + __shfl_xor(send, 8);
        }
        tot[r] = ((r << 6) + lane < N_LAGS) ? total : -__builtin_inff();
    }

    float w1 = tot[0], w2 = -__builtin_inff();
    int   j1 = lane;
    #pragma unroll
    for (int r = 1; r < 4; ++r) {
        float c = tot[r];
        bool take = (c > w1);
        float lose = take ? w1 : c;
        if (take) { w1 = c; j1 = (r << 6) + lane; }
        w2 = fmaxf(w2, lose);
    }
    #pragma unroll
    for (int m = 1; m < 64; m <<= 1) {
        float ov1 = __shfl_xor(w1, m);
        float ov2 = __shfl_xor(w2, m);
        int   oi1 = __shfl_xor(j1, m);
        bool take = (ov1 > w1) || (ov1 == w1 && oi1 < j1);
        float lose = take ? w1 : ov1;
        if (take) { w1 = ov1; j1 = oi1; }
        w2 = fmaxf(fmaxf(w2, ov2), lose);
    }

    if (w1 - w2 > GAP_B32) {
        if (lane == 0) {
            float period = (float)(j1 + MIN_PERIOD);
            float f0 = SR_F / (period + 1e-8f);
            out[bf] = fminf(fmaxf(f0, 50.0f), 500.0f);
        }
        return;
    }

    // =============== tier-3: fp64 (exact argmax), very rare ===============
    double dtot[4];
    #pragma unroll
    for (int r = 0; r < 4; ++r) {
        const int g  = (r << 2) + qd;
        const int p0 = MIN_PERIOD + (g << 4);
        double dacc[16];
        #pragma unroll
        for (int j = 0; j < 16; ++j) dacc[j] = 0.0;
        if (g < 14) {
            const int n16 = (FRAME_LEN - p0 + 15) >> 4;
            #pragma unroll
            for (int k = 0; k < 2; ++k) {
                const int ch = seg + (k << 4);
                if (ch < n16) {
                    const int t  = ch << 4;
                    const int qa = t >> 2;
                    const int qw = (t + p0) >> 2;
                    float a[16], w[32];
                    #pragma unroll
                    for (int u = 0; u < 4; ++u) {
                        float4 v = s4[swz(qa + u)];
                        a[4*u+0]=v.x; a[4*u+1]=v.y; a[4*u+2]=v.z; a[4*u+3]=v.w;
                    }
                    #pragma unroll
                    for (int u = 0; u < 8; ++u) {
                        float4 v = s4[swz(qw + u)];
                        w[4*u+0]=v.x; w[4*u+1]=v.y; w[4*u+2]=v.z; w[4*u+3]=v.w;
                    }
                    #pragma unroll
                    for (int j = 0; j < 16; ++j) {
                        #pragma unroll
                        for (int i = 0; i < 16; ++i)
                            dacc[j] = fma((double)a[i], (double)w[i + j], dacc[j]);
                    }
                }
            }
        }
        double u8[8], u4[4], u2[2], dtotal;
        #pragma unroll
        for (int i = 0; i < 8; ++i) {
            double lo = dacc[2*i], hi = dacc[2*i+1];
            double keep = s0 ? hi : lo, send = s0 ? lo : hi;
            u8[i] = keep + __shfl_xor(send, 1);
        }
        #pragma unroll
        for (int i = 0; i < 4; ++i) {
            double lo = u8[2*i], hi = u8[2*i+1];
            double keep = s1 ? hi : lo, send = s1 ? lo : hi;
            u4[i] = keep + __shfl_xor(send, 2);
        }
        #pragma unroll
        for (int i = 0; i < 2; ++i) {
            double lo = u4[2*i], hi = u4[2*i+1];
            double keep = s2 ? hi : lo, send = s2 ? lo : hi;
            u2[i] = keep + __shfl_xor(send, 4);
        }
        {
            double lo = u2[0], hi = u2[1];
            double keep = s3 ? hi : lo, send = s3 ? lo : hi;
            dtotal = keep + __shfl_xor(send, 8);
        }
        dtot[r] = ((r << 6) + lane < N_LAGS) ? dtotal : -__builtin_inf();
    }
    double dv1 = dtot[0];
    int    di1 = lane;
    #pragma unroll
    for (int r = 1; r < 4; ++r) {
        double c = dtot[r];
        if (c > dv1) { dv1 = c; di1 = (r << 6) + lane; }
    }
    #pragma unroll
    for (int m = 1; m < 64; m <<= 1) {
        double o = __shfl_xor(dv1, m);
        int   oi = __shfl_xor(di1, m);
        if (o > dv1 || (o == dv1 && oi < di1)) { dv1 = o; di1 = oi; }
    }
    if (lane == 0) {
        float period = (float)(di1 + MIN_PERIOD);
        float f0 = SR_F / (period + 1e-8f);
        out[bf] = fminf(fmaxf(f0, 50.0f), 500.0f);
    }
}

extern "C" void kernel_launch(void* const* d_in, const int* in_sizes, int n_in,
                              void* d_out, int out_size, void* d_ws, size_t ws_size,
                              hipStream_t stream) {
    const float* wav = (const float*)d_in[0]; // (64, 1, 163840) fp32
    float* out = (float*)d_out;               // (64, 641) fp32
    const int n_blocks = (64 * N_FRAMES) / FPB;   // 10256
    f0_kernel<<<n_blocks, 256, 0, stream>>>(wav, out);
}

// Round 9
// 141.228 us; speedup vs baseline: 4.8378x; 1.0634x over previous
//
#include <hip/hip_runtime.h>

// F0 via autocorrelation argmax — round 9: MFMA 3-tier, 8 frames/block.
//   SR=16000, HOP=256, FRAME_LEN=512, pad=256, T=163840, B=64, n_frames=641
//   lags p in [32,256). Normalization is a positive per-frame scalar ->
//   argmax of RAW autocorrelation equals reference argmax.
//
// GEMM cast (validated r8, absmax 0.0): y = frame zero-extended,
//   A[m,k]=y[k-16m], B[k,n]=y[k+32+n] => D[m,n]=AC[32+16m+n]
//   16 chained mfma_f32_16x16x32_f16 (K=512) give all 224 lags.
//
// Round-8 lesson (counters): nothing saturated (Mfma 4%, VALU 36%, occ 19%);
// the VALU tier-2 register tile (~4100 cyc) fired often, and 10k short
// blocks looked dispatch/ramp-limited. Fixes:
//  (a) tier-2 is now an MFMA refinement: x = hi + lo (double-f16 split),
//      chain 32 more MFMA (hi*lo + lo*hi) onto the tier-1 acc; rigorous
//      error E2 = 1e-4*Q + 0.02 -> exact fp64 tier-3 fires ~1-2%.
//  (b) 512-thread blocks, one frame per wave, 8 frames/block -> 5128 blocks.
//
// Tiers: accept iff top2 gap > 2*E; E1 = 2^-10*Q + 0.05 (f16 products,
// Cauchy-Schwarz; fp32 accum 512*2^-24*Q < 0.05). E2 as above. Tier-3 =
// fp64 register tile (exact argmax; matches np reference bit-for-bit).

#define SR_F 16000.0f
#define HOP 256
#define FRAME_LEN 512
#define PAD 256
#define T_LEN 163840
#define N_FRAMES 641
#define MIN_PERIOD 32
#define N_LAGS 224
#define FPB 8            // frames per block = waves per block (512 threads)

typedef _Float16 half8 __attribute__((ext_vector_type(8)));
typedef float floatx4 __attribute__((ext_vector_type(4)));

__device__ __forceinline__ int swz(int q) { return q ^ ((q >> 3) & 7); }

__device__ __forceinline__ unsigned int pkh(float a, float b) {
    unsigned short ha = __builtin_bit_cast(unsigned short, (_Float16)a);
    unsigned short hb = __builtin_bit_cast(unsigned short, (_Float16)b);
    return (unsigned int)ha | ((unsigned int)hb << 16);
}

// write even copy (elem e = Y[e-240]) + odd copy (elem e = Y[e-239]) from
// packed dwords u10,u11 (elems 4L..4L+3) and u20,u21 (elems 4L+256..4L+259)
__device__ __forceinline__ void write_copies(unsigned int* e, unsigned int* o,
                                             unsigned int u10, unsigned int u11,
                                             unsigned int u20, unsigned int u21,
                                             int lane) {
    e[120 + 2*lane] = u10;  e[121 + 2*lane] = u11;
    e[248 + 2*lane] = u20;  e[249 + 2*lane] = u21;
    unsigned int a  = __shfl(u10, (lane + 1) & 63);
    unsigned int bb = __shfl(u20, (lane + 1) & 63);
    unsigned int n1 = (lane == 63) ? bb : a;
    unsigned int n2 = (lane == 63) ? 0u : bb;
    o[120 + 2*lane] = (u10 >> 16) | (u11 << 16);
    o[121 + 2*lane] = (u11 >> 16) | (n1 << 16);
    o[248 + 2*lane] = (u20 >> 16) | (u21 << 16);
    o[249 + 2*lane] = (u21 >> 16) | (n2 << 16);
    if (lane == 0) o[119] = u10 << 16;   // {Y[-1]=0, Y[0]}
}

__global__ __launch_bounds__(512, 4) void f0_kernel(const float* __restrict__ wav,
                                                    float* __restrict__ out) {
    // per-wave slice: ye(400) yo(400) le(400) loo(400) dwords = 6400 B
    __shared__ unsigned int yw[FPB][1600];

    const int tid  = threadIdx.x;
    const int wv   = tid >> 6;
    const int lane = tid & 63;
    const int bf   = blockIdx.x * FPB + wv;       // 5128*8 == 41024
    const int b    = bf / N_FRAMES;
    const int f    = bf - b * N_FRAMES;
    const float* __restrict__ x = wav + (size_t)b * T_LEN;
    unsigned int* ye  = yw[wv];
    unsigned int* yo  = ye + 400;
    unsigned int* le  = ye + 800;
    unsigned int* loo = ye + 1200;
    const int base = f * HOP - PAD;
    const bool fast = (f != 0 && f != N_FRAMES - 1);

    // ---- zero hi-copy margins: dwords [0,120) and [375,400) ----
    ye[lane] = 0u; yo[lane] = 0u;
    if (lane < 56) { ye[64 + lane] = 0u; yo[64 + lane] = 0u; }
    if (lane < 25) { ye[375 + lane] = 0u; yo[375 + lane] = 0u; }

    float qen = 0.0f;
    if (fast) {
        const float4* g4 = (const float4*)(x + base);  // aligned, in-bounds
        float4 c1 = g4[lane];
        float4 c2 = g4[lane + 64];
        qen = c1.x*c1.x + c1.y*c1.y + c1.z*c1.z + c1.w*c1.w
            + c2.x*c2.x + c2.y*c2.y + c2.z*c2.z + c2.w*c2.w;
        write_copies(ye, yo, pkh(c1.x, c1.y), pkh(c1.z, c1.w),
                             pkh(c2.x, c2.y), pkh(c2.z, c2.w), lane);
    } else {
        for (int t = lane; t < FRAME_LEN; t += 64) {
            int idx = base + t;
            if (idx < 0) idx = -idx;
            if (idx >= T_LEN) idx = 2 * (T_LEN - 1) - idx;
            float v = x[idx];
            qen = __builtin_fmaf(v, v, qen);
            unsigned short h = __builtin_bit_cast(unsigned short, (_Float16)v);
            ((unsigned short*)ye)[240 + t] = h;
            ((unsigned short*)yo)[239 + t] = h;
        }
    }
    __threadfence_block();

    #pragma unroll
    for (int m = 1; m < 64; m <<= 1) qen += __shfl_xor(qen, m);

    // ---------------- tier-1: 16 MFMA (hi*hi) ----------------
    const int qd = lane >> 4;       // quad
    const int nn = lane & 15;       // A-row m / B-col n
    const int par = nn & 1;
    const unsigned int* ybh = par ? yo : ye;
    const int wA0 = 120 + 4*qd - 8*nn;
    const int wB0 = 136 + 4*qd + ((nn - par) >> 1);

    floatx4 acc = {0.f, 0.f, 0.f, 0.f};
    #pragma unroll
    for (int c = 0; c < 16; ++c) {
        uint4 au = *(const uint4*)(ye + (wA0 + 16*c));
        const unsigned int* pb = ybh + (wB0 + 16*c);
        uint4 bu; bu.x = pb[0]; bu.y = pb[1]; bu.z = pb[2]; bu.w = pb[3];
        acc = __builtin_amdgcn_mfma_f32_16x16x32_f16(
            __builtin_bit_cast(half8, au), __builtin_bit_cast(half8, bu),
            acc, 0, 0, 0);
    }

    // ---- top-2 (per-lane over 4 regs, then 64-lane butterfly) ----
    float v1 = acc[0];
    int   i1 = 64*qd + nn;
    float v2 = -__builtin_inff();
    #pragma unroll
    for (int r = 1; r < 4; ++r) {
        float cv = (4*qd + r < 14) ? acc[r] : -__builtin_inff();
        bool take = (cv > v1);
        float lose = take ? v1 : cv;
        if (take) { v1 = cv; i1 = 64*qd + 16*r + nn; }
        v2 = fmaxf(v2, lose);
    }
    #pragma unroll
    for (int m = 1; m < 64; m <<= 1) {
        float ov1 = __shfl_xor(v1, m);
        float ov2 = __shfl_xor(v2, m);
        int   oi1 = __shfl_xor(i1, m);
        bool take = (ov1 > v1) || (ov1 == v1 && oi1 < i1);
        float lose = take ? v1 : ov1;
        if (take) { v1 = ov1; i1 = oi1; }
        v2 = fmaxf(fmaxf(v2, ov2), lose);
    }

    const float E1 = 9.765625e-4f * qen + 0.05f;
    if (v1 - v2 > 2.0f * E1) {
        if (lane == 0) {
            float period = (float)(i1 + MIN_PERIOD);
            float f0 = SR_F / (period + 1e-8f);
            out[bf] = fminf(fmaxf(f0, 50.0f), 500.0f);
        }
        return;
    }

    // ======== tier-2: double-f16 split, +32 MFMA (hi*lo + lo*hi) ========
    // zero lo-copy margins, then stage lo = f16(x - (float)f16(x))
    le[lane] = 0u; loo[lane] = 0u;
    if (lane < 56) { le[64 + lane] = 0u; loo[64 + lane] = 0u; }
    if (lane < 25) { le[375 + lane] = 0u; loo[375 + lane] = 0u; }
    if (fast) {
        const float4* g4 = (const float4*)(x + base);  // L2-hot reload
        float4 c1 = g4[lane];
        float4 c2 = g4[lane + 64];
        float l0 = c1.x - (float)(_Float16)c1.x;
        float l1 = c1.y - (float)(_Float16)c1.y;
        float l2 = c1.z - (float)(_Float16)c1.z;
        float l3 = c1.w - (float)(_Float16)c1.w;
        float l4 = c2.x - (float)(_Float16)c2.x;
        float l5 = c2.y - (float)(_Float16)c2.y;
        float l6 = c2.z - (float)(_Float16)c2.z;
        float l7 = c2.w - (float)(_Float16)c2.w;
        write_copies(le, loo, pkh(l0, l1), pkh(l2, l3),
                              pkh(l4, l5), pkh(l6, l7), lane);
    } else {
        for (int t = lane; t < FRAME_LEN; t += 64) {
            int idx = base + t;
            if (idx < 0) idx = -idx;
            if (idx >= T_LEN) idx = 2 * (T_LEN - 1) - idx;
            float v = x[idx];
            float l = v - (float)(_Float16)v;
            unsigned short h = __builtin_bit_cast(unsigned short, (_Float16)l);
            ((unsigned short*)le)[240 + t] = h;
            ((unsigned short*)loo)[239 + t] = h;
        }
    }
    __threadfence_block();

    const unsigned int* ybl = par ? loo : le;
    #pragma unroll
    for (int c = 0; c < 16; ++c) {              // hi * lo
        uint4 au = *(const uint4*)(ye + (wA0 + 16*c));
        const unsigned int* pb = ybl + (wB0 + 16*c);
        uint4 bu; bu.x = pb[0]; bu.y = pb[1]; bu.z = pb[2]; bu.w = pb[3];
        acc = __builtin_amdgcn_mfma_f32_16x16x32_f16(
            __builtin_bit_cast(half8, au), __builtin_bit_cast(half8, bu),
            acc, 0, 0, 0);
    }
    #pragma unroll
    for (int c = 0; c < 16; ++c) {              // lo * hi
        uint4 au = *(const uint4*)(le + (wA0 + 16*c));
        const unsigned int* pb = ybh + (wB0 + 16*c);
        uint4 bu; bu.x = pb[0]; bu.y = pb[1]; bu.z = pb[2]; bu.w = pb[3];
        acc = __builtin_amdgcn_mfma_f32_16x16x32_f16(
            __builtin_bit_cast(half8, au), __builtin_bit_cast(half8, bu),
            acc, 0, 0, 0);
    }

    // top-2 again on refined acc
    v1 = acc[0]; i1 = 64*qd + nn; v2 = -__builtin_inff();
    #pragma unroll
    for (int r = 1; r < 4; ++r) {
        float cv = (4*qd + r < 14) ? acc[r] : -__builtin_inff();
        bool take = (cv > v1);
        float lose = take ? v1 : cv;
        if (take) { v1 = cv; i1 = 64*qd + 16*r + nn; }
        v2 = fmaxf(v2, lose);
    }
    #pragma unroll
    for (int m = 1; m < 64; m <<= 1) {
        float ov1 = __shfl_xor(v1, m);
        float ov2 = __shfl_xor(v2, m);
        int   oi1 = __shfl_xor(i1, m);
        bool take = (ov1 > v1) || (ov1 == v1 && oi1 < i1);
        float lose = take ? v1 : ov1;
        if (take) { v1 = ov1; i1 = oi1; }
        v2 = fmaxf(fmaxf(v2, ov2), lose);
    }

    const float E2 = 1.0e-4f * qen + 0.02f;
    if (v1 - v2 > 2.0f * E2) {
        if (lane == 0) {
            float period = (float)(i1 + MIN_PERIOD);
            float f0 = SR_F / (period + 1e-8f);
            out[bf] = fminf(fmaxf(f0, 50.0f), 500.0f);
        }
        return;
    }

    // =============== tier-3: fp64 register tile (exact), rare ===============
    float* sw = (float*)ye;    // 576 floats, overwrites hi copies (terminal)
    if (fast) {
        const float4* g4 = (const float4*)(x + base);
        ((float4*)sw)[swz(lane)]      = g4[lane];
        ((float4*)sw)[swz(lane + 64)] = g4[lane + 64];
        if (lane < 16) ((float4*)sw)[swz(lane + 128)] = make_float4(0.f,0.f,0.f,0.f);
    } else {
        for (int t = lane; t < FRAME_LEN; t += 64) {
            int idx = base + t;
            if (idx < 0) idx = -idx;
            if (idx >= T_LEN) idx = 2 * (T_LEN - 1) - idx;
            sw[(swz(t >> 2) << 2) | (t & 3)] = x[idx];
        }
        int t = FRAME_LEN + lane;
        sw[(swz(t >> 2) << 2) | (t & 3)] = 0.0f;
    }
    __threadfence_block();

    const float4* s4 = (const float4*)sw;
    const int seg = lane & 15;
    const bool s0 = (seg & 1), s1 = (seg & 2), s2 = (seg & 4), s3 = (seg & 8);

    double dtot[4];
    #pragma unroll
    for (int r = 0; r < 4; ++r) {
        const int g  = (r << 2) + qd;
        const int p0 = MIN_PERIOD + (g << 4);
        double dacc[16];
        #pragma unroll
        for (int j = 0; j < 16; ++j) dacc[j] = 0.0;
        if (g < 14) {
            const int n16 = (FRAME_LEN - p0 + 15) >> 4;
            #pragma unroll
            for (int k = 0; k < 2; ++k) {
                const int ch = seg + (k << 4);
                if (ch < n16) {
                    const int t  = ch << 4;
                    const int qa = t >> 2;
                    const int qw = (t + p0) >> 2;
                    float a[16], w[32];
                    #pragma unroll
                    for (int u = 0; u < 4; ++u) {
                        float4 v = s4[swz(qa + u)];
                        a[4*u+0]=v.x; a[4*u+1]=v.y; a[4*u+2]=v.z; a[4*u+3]=v.w;
                    }
                    #pragma unroll
                    for (int u = 0; u < 8; ++u) {
                        float4 v = s4[swz(qw + u)];
                        w[4*u+0]=v.x; w[4*u+1]=v.y; w[4*u+2]=v.z; w[4*u+3]=v.w;
                    }
                    #pragma unroll
                    for (int j = 0; j < 16; ++j) {
                        #pragma unroll
                        for (int i = 0; i < 16; ++i)
                            dacc[j] = fma((double)a[i], (double)w[i + j], dacc[j]);
                    }
                }
            }
        }
        double u8[8], u4[4], u2[2], dtotal;
        #pragma unroll
        for (int i = 0; i < 8; ++i) {
            double lo = dacc[2*i], hi = dacc[2*i+1];
            double keep = s0 ? hi : lo, send = s0 ? lo : hi;
            u8[i] = keep + __shfl_xor(send, 1);
        }
        #pragma unroll
        for (int i = 0; i < 4; ++i) {
            double lo = u8[2*i], hi = u8[2*i+1];
            double keep = s1 ? hi : lo, send = s1 ? lo : hi;
            u4[i] = keep + __shfl_xor(send, 2);
        }
        #pragma unroll
        for (int i = 0; i < 2; ++i) {
            double lo = u4[2*i], hi = u4[2*i+1];
            double keep = s2 ? hi : lo, send = s2 ? lo : hi;
            u2[i] = keep + __shfl_xor(send, 4);
        }
        {
            double lo = u2[0], hi = u2[1];
            double keep = s3 ? hi : lo, send = s3 ? lo : hi;
            dtotal = keep + __shfl_xor(send, 8);
        }
        dtot[r] = ((r << 6) + lane < N_LAGS) ? dtotal : -__builtin_inf();
    }
    double dv1 = dtot[0];
    int    di1 = lane;
    #pragma unroll
    for (int r = 1; r < 4; ++r) {
        double c = dtot[r];
        if (c > dv1) { dv1 = c; di1 = (r << 6) + lane; }
    }
    #pragma unroll
    for (int m = 1; m < 64; m <<= 1) {
        double o = __shfl_xor(dv1, m);
        int   oi = __shfl_xor(di1, m);
        if (o > dv1 || (o == dv1 && oi < di1)) { dv1 = o; di1 = oi; }
    }
    if (lane == 0) {
        float period = (float)(di1 + MIN_PERIOD);
        float f0 = SR_F / (period + 1e-8f);
        out[bf] = fminf(fmaxf(f0, 50.0f), 500.0f);
    }
}

extern "C" void kernel_launch(void* const* d_in, const int* in_sizes, int n_in,
                              void* d_out, int out_size, void* d_ws, size_t ws_size,
                              hipStream_t stream) {
    const float* wav = (const float*)d_in[0]; // (64, 1, 163840) fp32
    float* out = (float*)d_out;               // (64, 641) fp32
    const int n_blocks = (64 * N_FRAMES) / FPB;   // 5128
    f0_kernel<<<n_blocks, 512, 0, stream>>>(wav, out);
}